// Round 5
// baseline (504.540 us; speedup 1.0000x reference)
//
#include <hip/hip_runtime.h>
#include <hip/hip_fp16.h>
#include <math.h>

typedef _Float16 half_t;
typedef _Float16 half8 __attribute__((ext_vector_type(8)));
typedef float f32x4 __attribute__((ext_vector_type(4)));

#define MFMA(a, b, c) __builtin_amdgcn_mfma_f32_16x16x32_f16((a), (b), (c), 0, 0, 0)
// LDS-only barrier: waits lgkmcnt (LDS) but leaves global (vmcnt) prefetch loads
// in flight. Legal: all cross-wave data flows through LDS; 'out' is never re-read.
#define BARRIER() asm volatile("s_waitcnt lgkmcnt(0)\n\ts_barrier" ::: "memory")

static constexpr float kScale = 0.2041241452319315f;  // 24^-0.5
static constexpr int RS   = 104;  // hn / xn / rbuf row stride (halves)
static constexpr int QSTR = 200;  // qbuf row stride (Q|K -> O)
static constexpr int VTS  = 72;   // vT row stride (pbuf aliases per-head slice)
static constexpr int H1S  = 392;  // h1 half row stride

struct W3 { half8 b0, b1, b2; float bias; };

__device__ __forceinline__ W3 ld_w3(const half_t* w, const float* bv, int n0, int qo) {
  W3 r;
  const half_t* wp = w + (size_t)n0 * 96 + qo;
  r.b0 = *(const half8*)(wp);
  r.b1 = *(const half8*)(wp + 32);
  r.b2 = *(const half8*)(wp + 64);
  r.bias = bv[n0];
  return r;
}

__device__ __forceinline__ void qkv_tile(const W3& w, int t, int l15, int quad,
                                         const half8 (&af)[4][3],
                                         half_t* qbuf, half_t* vT) {
  f32x4 acc[4] = {{0,0,0,0},{0,0,0,0},{0,0,0,0},{0,0,0,0}};
#pragma unroll
  for (int g = 0; g < 4; ++g) acc[g] = MFMA(af[g][0], w.b0, acc[g]);
#pragma unroll
  for (int g = 0; g < 4; ++g) acc[g] = MFMA(af[g][1], w.b1, acc[g]);
#pragma unroll
  for (int g = 0; g < 4; ++g) acc[g] = MFMA(af[g][2], w.b2, acc[g]);
  int n0 = t * 16 + l15;
  if (t < 12) {                      // Q (scaled) and K -> qbuf col n0
    float sc_ = (t < 6) ? kScale : 1.f;
#pragma unroll
    for (int g = 0; g < 4; ++g)
#pragma unroll
      for (int r = 0; r < 4; ++r)
        qbuf[(g * 16 + quad * 4 + r) * QSTR + n0] = (half_t)((acc[g][r] + w.bias) * sc_);
  } else {                           // V -> vT [head][c][token]
    int vc = n0 - 192;
    int hd = vc / 24, c = vc - hd * 24;
#pragma unroll
    for (int g = 0; g < 4; ++g)
#pragma unroll
      for (int r = 0; r < 4; ++r)
        vT[hd * 24 * VTS + c * VTS + g * 16 + quad * 4 + r] = (half_t)(acc[g][r] + w.bias);
  }
}

__device__ __forceinline__ void fc1_tile(const W3& w, int t, int l15, int quad,
                                         const half8 (&a0f)[3], const half8 (&a1f)[3],
                                         half_t* h1h) {
  f32x4 a0 = {0,0,0,0}, a1 = {0,0,0,0};
  a0 = MFMA(a0f[0], w.b0, a0); a1 = MFMA(a1f[0], w.b0, a1);
  a0 = MFMA(a0f[1], w.b1, a0); a1 = MFMA(a1f[1], w.b1, a1);
  a0 = MFMA(a0f[2], w.b2, a0); a1 = MFMA(a1f[2], w.b2, a1);
  int n0 = t * 16 + l15;
#pragma unroll
  for (int g2 = 0; g2 < 2; ++g2) {
    const f32x4& ac = g2 ? a1 : a0;
#pragma unroll
    for (int r = 0; r < 4; ++r) {
      float vvv = ac[r] + w.bias;
      // GELU: v * sigmoid(v*(1.5957691 + 0.14270963*v^2))
      float u = vvv * (1.5957691216f + 0.1427096322f * vvv * vvv);
      float g = vvv * __builtin_amdgcn_rcpf(1.f + __expf(-u));
      h1h[(g2 * 16 + quad * 4 + r) * H1S + n0] = (half_t)g;
    }
  }
}

// P5: one 32-row half; 2-deep fc1 weight pipeline (f1A/f1B only -> 26 VGPR).
template <bool LOADF1>
__device__ __forceinline__ void p5_pass(const half8 (&a0f)[3], const half8 (&a1f)[3],
                                        int wave, int l15, int quad, int qo,
                                        half_t* h1h, const half_t* fc1w,
                                        const float* fc1b, W3& f1A, W3& f1B) {
  if (LOADF1) {
    f1A = ld_w3(fc1w, fc1b, wave * 16 + l15, qo);
    f1B = ld_w3(fc1w, fc1b, (wave + 4) * 16 + l15, qo);
  }
  fc1_tile(f1A, wave, l15, quad, a0f, a1f, h1h);
  f1A = ld_w3(fc1w, fc1b, (wave + 8) * 16 + l15, qo);
  fc1_tile(f1B, wave + 4, l15, quad, a0f, a1f, h1h);
  f1B = ld_w3(fc1w, fc1b, (wave + 12) * 16 + l15, qo);
  fc1_tile(f1A, wave + 8, l15, quad, a0f, a1f, h1h);
  f1A = ld_w3(fc1w, fc1b, (wave + 16) * 16 + l15, qo);
  fc1_tile(f1B, wave + 12, l15, quad, a0f, a1f, h1h);
  f1B = ld_w3(fc1w, fc1b, (wave + 20) * 16 + l15, qo);
  fc1_tile(f1A, wave + 16, l15, quad, a0f, a1f, h1h);
  fc1_tile(f1B, wave + 20, l15, quad, a0f, a1f, h1h);
}

// P6: fc2 + residual -> out. A-operand streamed from LDS (no a2[12] residency);
// one bf[12] buffer; t-loop kept rolled to bound registers.
__device__ __forceinline__ void p6_pass(int hb, int wave, int l15, int quad, int qo,
                                        int chh, int wh, int ww, int bb,
                                        const half_t* h1h, const half_t* rbuf,
                                        const half_t* fc2w, const float* fc2b,
                                        float* out) {
  int rt = wave >> 1;
  const half_t* hp = h1h + (rt * 16 + l15) * H1S + qo;
#pragma unroll 1
  for (int i = 0; i < 3; ++i) {
    int t = chh * 3 + i;
    half8 bf[12];
#pragma unroll
    for (int kt = 0; kt < 12; ++kt)
      bf[kt] = *(const half8*)(fc2w + (size_t)(t * 16 + l15) * 384 + kt * 32 + qo);
    f32x4 acc = {0, 0, 0, 0};
#pragma unroll
    for (int kt = 0; kt < 12; ++kt) {
      half8 a2 = *(const half8*)(hp + kt * 32);
      acc = MFMA(a2, bf[kt], acc);
    }
    int col = t * 16 + l15;
    float bias = fc2b[col];
#pragma unroll
    for (int r = 0; r < 4; ++r) {
      int tok = hb * 32 + rt * 16 + quad * 4 + r;
      int sr = (wh * 8 + (tok >> 3) + 4) & 63;
      int sc = (ww * 8 + (tok & 7) + 4) & 63;
      out[((size_t)bb * 4096 + sr * 64 + sc) * 96 + col] =
          (float)rbuf[tok * RS + col] + acc[r] + bias;
    }
  }
}

// ---- weights -> fp16, plus rel-pos bias expanded to [head][i][j] fp32 (64 KB)
__global__ __launch_bounds__(256) void k_convert(const float* __restrict__ qkv_w,
                                                 const float* __restrict__ proj_w,
                                                 const float* __restrict__ fc1_w,
                                                 const float* __restrict__ fc2_w,
                                                 const float* __restrict__ tbl,
                                                 half_t* __restrict__ wbuf,
                                                 float* __restrict__ biasT) {
  int i = blockIdx.x * 256 + threadIdx.x;
  if (i < 27648)        wbuf[i] = (half_t)qkv_w[i];
  else if (i < 36864)   wbuf[i] = (half_t)proj_w[i - 27648];
  else if (i < 73728)   wbuf[i] = (half_t)fc1_w[i - 36864];
  else if (i < 110592)  wbuf[i] = (half_t)fc2_w[i - 73728];
  else if (biasT != nullptr) {
    int j = i - 110592;                  // [head][i][j] : 4 * 64 * 64
    int h = j >> 12, rem = j & 4095;
    int ii = rem >> 6, jj = rem & 63;
    int ih = ii >> 3, iw = ii & 7, jh = jj >> 3, jw = jj & 7;
    biasT[j] = tbl[((ih - jh + 7) * 15 + (iw - jw + 7)) * 4 + h];
  }
}

// ===== whole Swin block fused; 40960 B LDS -> 4 blocks/CU; lgkm-only barriers;
// every phase register-budgeted to fit the 128-VGPR/thread cap without spills.
// Map:  hn@0 (P0) -> qbuf@0 25600 + vT@25600 13824+pad (P1-P2)
//       -> rbuf@0 13312 + xn@13312 13312 (D) -> h1h@13312 25088 (MLP, over xn)
__global__ __launch_bounds__(256, 4) void k_swin(
    const float* __restrict__ x,
    const float* __restrict__ n1g, const float* __restrict__ n1b,
    const half_t* __restrict__ qkvw, const float* __restrict__ qkv_b,
    const float* __restrict__ tbl_g, const float* __restrict__ biasT,
    const half_t* __restrict__ projw, const float* __restrict__ proj_b,
    const float* __restrict__ n2g, const float* __restrict__ n2b,
    const half_t* __restrict__ fc1w, const float* __restrict__ fc1b,
    const half_t* __restrict__ fc2w, const float* __restrict__ fc2b,
    float* __restrict__ out) {
  __shared__ __attribute__((aligned(16))) unsigned char smem[40960];
  half_t* hn   = (half_t*)smem;
  half_t* qbuf = (half_t*)smem;
  half_t* vT   = (half_t*)(smem + 25600);
  half_t* rbuf = (half_t*)smem;
  half_t* xn   = (half_t*)(smem + 13312);
  half_t* h1h  = (half_t*)(smem + 13312);

  int tid = threadIdx.x;
  int wave = tid >> 6, lane = tid & 63;
  int l15 = lane & 15, quad = lane >> 4;
  int qo = quad * 8, chh = wave & 1;
  int blk = blockIdx.x;                        // bb*64 + wh*8 + ww
  int bb = blk >> 6, wh = (blk >> 3) & 7, ww = blk & 7;

  // ---- P0: LN1 (x loads first; first two QKV weight tiles prefetched)
  float v[24];
  {
    int tok = wave * 16 + l15;
    int sr = (wh * 8 + (tok >> 3) + 4) & 63;
    int sc = (ww * 8 + (tok & 7) + 4) & 63;
    const float* rp = x + ((size_t)bb * 4096 + sr * 64 + sc) * 96;
#pragma unroll
    for (int kt = 0; kt < 3; ++kt) {
      float4 a = *(const float4*)(rp + kt * 32 + qo);
      float4 b = *(const float4*)(rp + kt * 32 + qo + 4);
      v[kt*8+0]=a.x; v[kt*8+1]=a.y; v[kt*8+2]=a.z; v[kt*8+3]=a.w;
      v[kt*8+4]=b.x; v[kt*8+5]=b.y; v[kt*8+6]=b.z; v[kt*8+7]=b.w;
    }
  }
  W3 qA = ld_w3(qkvw, qkv_b, wave * 16 + l15, qo);
  W3 qB = ld_w3(qkvw, qkv_b, (wave + 4) * 16 + l15, qo);
  {
    int tok = wave * 16 + l15;
    float s1 = 0.f, s2 = 0.f;
#pragma unroll
    for (int c = 0; c < 24; ++c) { s1 += v[c]; s2 += v[c] * v[c]; }
    s1 += __shfl_xor(s1, 16); s1 += __shfl_xor(s1, 32);
    s2 += __shfl_xor(s2, 16); s2 += __shfl_xor(s2, 32);
    float mu = s1 * (1.f / 96.f);
    float inv = rsqrtf(fmaxf(s2 * (1.f / 96.f) - mu * mu, 0.f) + 1e-5f);
#pragma unroll
    for (int kt = 0; kt < 3; ++kt) {
      int c0 = kt * 32 + qo;
      float4 g0 = *(const float4*)(n1g + c0);
      float4 g1 = *(const float4*)(n1g + c0 + 4);
      float4 b0 = *(const float4*)(n1b + c0);
      float4 b1 = *(const float4*)(n1b + c0 + 4);
      float gg[8] = {g0.x,g0.y,g0.z,g0.w,g1.x,g1.y,g1.z,g1.w};
      float bv[8] = {b0.x,b0.y,b0.z,b0.w,b1.x,b1.y,b1.z,b1.w};
      half8 hh;
#pragma unroll
      for (int j = 0; j < 8; ++j)
        hh[j] = (half_t)((v[kt*8+j] - mu) * inv * gg[j] + bv[j]);
      *(half8*)(&hn[tok * RS + kt * 32 + qo]) = hh;
    }
  }
  BARRIER();  // B0: hn visible

  // ---- P1pre: every wave pulls all A-fragments; then hn is dead
  W3 qC = ld_w3(qkvw, qkv_b, (wave + 8) * 16 + l15, qo);
  half8 af[4][3];
#pragma unroll
  for (int g = 0; g < 4; ++g)
#pragma unroll
    for (int kt = 0; kt < 3; ++kt)
      af[g][kt] = *(const half8*)(&hn[(g * 16 + l15) * RS + kt * 32 + qo]);
  BARRIER();  // B0b: hn consumed -> qbuf may overlay it

  // ---- P1: QKV GEMM, column-split, 2-deep weight pipeline
  {
    qkv_tile(qA, wave, l15, quad, af, qbuf, vT);
    qA = ld_w3(qkvw, qkv_b, (wave + 12) * 16 + l15, qo);
    qkv_tile(qB, wave + 4, l15, quad, af, qbuf, vT);
    if (wave < 2) qB = ld_w3(qkvw, qkv_b, (wave + 16) * 16 + l15, qo);
    qkv_tile(qC, wave + 8, l15, quad, af, qbuf, vT);
    qkv_tile(qA, wave + 12, l15, quad, af, qbuf, vT);
    if (wave < 2) qkv_tile(qB, wave + 16, l15, quad, af, qbuf, vT);
  }
  int head = wave;
  BARRIER();  // B1: Q,K,V staged

  // ---- P2: attention, wave = head; O stored per row-group (oacc 8 VGPR)
  {
    const half8 z8 = {};
    half8 kb[4], vb[2][2];
#pragma unroll
    for (int nt = 0; nt < 4; ++nt) {
      half8 t = *(const half8*)(&qbuf[(nt * 16 + l15) * QSTR + 96 + head * 24 + qo]);
      kb[nt] = (quad < 3) ? t : z8;
    }
#pragma unroll
    for (int nt = 0; nt < 2; ++nt)
#pragma unroll
      for (int kt = 0; kt < 2; ++kt)
        vb[nt][kt] = *(const half8*)(&vT[head * 24 * VTS + (nt * 16 + l15) * VTS + kt * 32 + qo]);

    int rj[4];
#pragma unroll
    for (int nt = 0; nt < 4; ++nt) {
      int j = nt * 16 + l15;
      int rr = wh * 8 + (j >> 3), cc = ww * 8 + (j & 7);
      rj[nt] = ((rr < 56) ? 0 : ((rr < 60) ? 1 : 2)) * 3 + ((cc < 56) ? 0 : ((cc < 60) ? 1 : 2));
    }

    half_t* pb = vT + head * 24 * VTS;   // wave-private alias over own vT slice

#pragma unroll
    for (int g2 = 0; g2 < 4; ++g2) {
      // bias loads issued first (global, overlap with QK MFMAs below)
      float btg[16];
      if (biasT != nullptr) {
#pragma unroll
        for (int r = 0; r < 4; ++r) {
          const float* bp = biasT + (head << 12) + ((g2 * 16 + quad * 4 + r) << 6) + l15;
#pragma unroll
          for (int nt = 0; nt < 4; ++nt) btg[r * 4 + nt] = bp[nt * 16];
        }
      }
      half8 qt = *(const half8*)(&qbuf[(g2 * 16 + l15) * QSTR + head * 24 + qo]);
      half8 qa = (quad < 3) ? qt : z8;
      f32x4 sv[4];
#pragma unroll
      for (int nt = 0; nt < 4; ++nt) {
        f32x4 a = {0, 0, 0, 0};
        sv[nt] = MFMA(qa, kb[nt], a);
      }
      float pinv[4];
#pragma unroll
      for (int r = 0; r < 4; ++r) {
        int i = g2 * 16 + quad * 4 + r;
        int ih = i >> 3, iw = i & 7;
        int rr = wh * 8 + ih, cc = ww * 8 + iw;
        int ri = ((rr < 56) ? 0 : ((rr < 60) ? 1 : 2)) * 3 + ((cc < 56) ? 0 : ((cc < 60) ? 1 : 2));
#pragma unroll
        for (int nt = 0; nt < 4; ++nt) {
          float bvv;
          if (biasT != nullptr) bvv = btg[r * 4 + nt];
          else {
            int j = nt * 16 + l15;
            bvv = tbl_g[((ih - (j >> 3) + 7) * 15 + (iw - (j & 7) + 7)) * 4 + head];
          }
          float val = sv[nt][r] + bvv;
          if (ri != rj[nt]) val -= 100.f;
          sv[nt][r] = val;
        }
        float mx = fmaxf(fmaxf(sv[0][r], sv[1][r]), fmaxf(sv[2][r], sv[3][r]));
        mx = fmaxf(mx, __shfl_xor(mx, 1));
        mx = fmaxf(mx, __shfl_xor(mx, 2));
        mx = fmaxf(mx, __shfl_xor(mx, 4));
        mx = fmaxf(mx, __shfl_xor(mx, 8));
        float sum = 0.f;
#pragma unroll
        for (int nt = 0; nt < 4; ++nt) {
          float e = __expf(sv[nt][r] - mx);
          sv[nt][r] = e;
          sum += e;
        }
        sum += __shfl_xor(sum, 1);
        sum += __shfl_xor(sum, 2);
        sum += __shfl_xor(sum, 4);
        sum += __shfl_xor(sum, 8);
        pinv[r] = __builtin_amdgcn_rcpf(sum);
      }
#pragma unroll
      for (int nt = 0; nt < 4; ++nt)
#pragma unroll
        for (int r = 0; r < 4; ++r)
          pb[(quad * 4 + r) * VTS + nt * 16 + l15] = (half_t)(sv[nt][r] * pinv[r]);
      __builtin_amdgcn_sched_barrier(0);
      half8 pa0 = *(const half8*)(&pb[l15 * VTS + qo]);
      half8 pa1 = *(const half8*)(&pb[l15 * VTS + 32 + qo]);
#pragma unroll
      for (int nt = 0; nt < 2; ++nt) {
        f32x4 a = {0, 0, 0, 0};
        a = MFMA(pa0, vb[nt][0], a);
        a = MFMA(pa1, vb[nt][1], a);
        // O-store per row-group: own head's Q cols, rows g2*16.. (wave-private;
        // quad-3 over-reads by neighbor heads are masked to zero on use)
        int c = nt * 16 + l15;
        if (c < 24)
#pragma unroll
          for (int r = 0; r < 4; ++r)
            qbuf[(g2 * 16 + quad * 4 + r) * QSTR + head * 24 + c] = (half_t)a[r];
      }
    }
  }
  // prefetch across B2: first three proj tiles, residual x, LN2 gamma/beta
  W3 pw0 = ld_w3(projw, proj_b, 0 * 16 + l15, qo);
  W3 pw1 = ld_w3(projw, proj_b, 1 * 16 + l15, qo);
  W3 pw2 = ld_w3(projw, proj_b, 2 * 16 + l15, qo);
  float xv[6][4];
#pragma unroll
  for (int r = 0; r < 4; ++r) {
    int tok2 = wave * 16 + quad * 4 + r;
    int sr = (wh * 8 + (tok2 >> 3) + 4) & 63;
    int sc = (ww * 8 + (tok2 & 7) + 4) & 63;
    const float* xp = x + ((size_t)bb * 4096 + sr * 64 + sc) * 96 + l15;
#pragma unroll
    for (int t = 0; t < 6; ++t) xv[t][r] = xp[t * 16];
  }
  float gn2[6], bn2[6];
#pragma unroll
  for (int t = 0; t < 6; ++t) { gn2[t] = n2g[t * 16 + l15]; bn2[t] = n2b[t * 16 + l15]; }
  BARRIER();  // B2: all heads' O columns visible

  // ---- D: proj (row-split, 3-deep pw pipeline) + residual + LN2 -> rbuf + xn
  W3 f1A, f1B;
  {
    half8 oa[3];
#pragma unroll
    for (int kt = 0; kt < 3; ++kt)
      oa[kt] = *(const half8*)(&qbuf[(wave * 16 + l15) * QSTR + kt * 32 + qo]);
    BARRIER();  // B2b: qbuf fully consumed -> rbuf/xn may overlay it
    float rv[6][4];
    float s1[4] = {0, 0, 0, 0}, s2[4] = {0, 0, 0, 0};
#define PROJ_STEP(PW, T)                                                     \
    {                                                                        \
      f32x4 a = {0, 0, 0, 0};                                                \
      a = MFMA(oa[0], PW.b0, a);                                             \
      a = MFMA(oa[1], PW.b1, a);                                             \
      a = MFMA(oa[2], PW.b2, a);                                             \
      _Pragma("unroll")                                                      \
      for (int r = 0; r < 4; ++r) {                                          \
        float vvv = xv[T][r] + a[r] + PW.bias;                               \
        rv[T][r] = vvv; s1[r] += vvv; s2[r] += vvv * vvv;                    \
      }                                                                      \
    }
    PROJ_STEP(pw0, 0); pw0 = ld_w3(projw, proj_b, 3 * 16 + l15, qo);
    PROJ_STEP(pw1, 1); pw1 = ld_w3(projw, proj_b, 4 * 16 + l15, qo);
    PROJ_STEP(pw2, 2); pw2 = ld_w3(projw, proj_b, 5 * 16 + l15, qo);
    PROJ_STEP(pw0, 3);
    PROJ_STEP(pw1, 4);
    PROJ_STEP(pw2, 5);
#undef PROJ_STEP
    float mu[4], nv[4];
#pragma unroll
    for (int r = 0; r < 4; ++r) {
      s1[r] += __shfl_xor(s1[r], 1); s1[r] += __shfl_xor(s1[r], 2);
      s1[r] += __shfl_xor(s1[r], 4); s1[r] += __shfl_xor(s1[r], 8);
      s2[r] += __shfl_xor(s2[r], 1); s2[r] += __shfl_xor(s2[r], 2);
      s2[r] += __shfl_xor(s2[r], 4); s2[r] += __shfl_xor(s2[r], 8);
      mu[r] = s1[r] * (1.f / 96.f);
      nv[r] = rsqrtf(fmaxf(s2[r] * (1.f / 96.f) - mu[r] * mu[r], 0.f) + 1e-5f);
    }
#pragma unroll
    for (int t = 0; t < 6; ++t) {
      int n0 = t * 16 + l15;
#pragma unroll
      for (int r = 0; r < 4; ++r) {
        int row = wave * 16 + quad * 4 + r;
        rbuf[row * RS + n0] = (half_t)rv[t][r];
        xn[row * RS + n0] = (half_t)((rv[t][r] - mu[r]) * nv[r] * gn2[t] + bn2[t]);
      }
    }
    // prefetch first two fc1 tiles (issued after rv/xv die; cross B3/B3b)
    f1A = ld_w3(fc1w, fc1b, wave * 16 + l15, qo);
    f1B = ld_w3(fc1w, fc1b, (wave + 4) * 16 + l15, qo);
  }
  BARRIER();  // B3: xn + rbuf ready

  // ---- MLP prelude: pull both halves' A-fragments (split lo/hi); xn then dead
  half8 a5lo[2][3], a5hi[2][3];
#pragma unroll
  for (int g = 0; g < 2; ++g)
#pragma unroll
    for (int kt = 0; kt < 3; ++kt) {
      a5lo[g][kt] = *(const half8*)(&xn[(g * 16 + l15) * RS + kt * 32 + qo]);
      a5hi[g][kt] = *(const half8*)(&xn[((g + 2) * 16 + l15) * RS + kt * 32 + qo]);
    }
  BARRIER();  // B3b: xn consumed -> h1h may overlay it

  // ---- MLP: two 32-row halves
  p5_pass<false>(a5lo[0], a5lo[1], wave, l15, quad, qo, h1h, fc1w, fc1b, f1A, f1B);
  BARRIER();  // B4
  p6_pass(0, wave, l15, quad, qo, chh, wh, ww, bb, h1h, rbuf, fc2w, fc2b, out);
  BARRIER();  // B5: h1h consumed -> reuse for hb=1
  p5_pass<true>(a5hi[0], a5hi[1], wave, l15, quad, qo, h1h, fc1w, fc1b, f1A, f1B);
  BARRIER();  // B6
  p6_pass(1, wave, l15, quad, qo, chh, wh, ww, bb, h1h, rbuf, fc2w, fc2b, out);
}

extern "C" void kernel_launch(void* const* d_in, const int* in_sizes, int n_in,
                              void* d_out, int out_size, void* d_ws, size_t ws_size,
                              hipStream_t stream) {
  const float* x      = (const float*)d_in[0];
  const float* n1g    = (const float*)d_in[1];
  const float* n1b    = (const float*)d_in[2];
  const float* qkv_w  = (const float*)d_in[3];
  const float* qkv_b  = (const float*)d_in[4];
  const float* rtbl   = (const float*)d_in[5];
  const float* proj_w = (const float*)d_in[6];
  const float* proj_b = (const float*)d_in[7];
  const float* n2g    = (const float*)d_in[8];
  const float* n2b    = (const float*)d_in[9];
  const float* fc1_w  = (const float*)d_in[10];
  const float* fc1_b  = (const float*)d_in[11];
  const float* fc2_w  = (const float*)d_in[12];
  const float* fc2_b  = (const float*)d_in[13];
  float* out = (float*)d_out;

  if (ws_size < 221184) return;
  half_t* wbuf = (half_t*)d_ws;
  float* biasT = (ws_size >= 221184 + 65536) ? (float*)((char*)d_ws + 221184) : nullptr;

  k_convert<<<496, 256, 0, stream>>>(qkv_w, proj_w, fc1_w, fc2_w, rtbl, wbuf, biasT);
  k_swin<<<4096, 256, 0, stream>>>(x, n1g, n1b, wbuf, qkv_b, rtbl, biasT,
                                   wbuf + 27648, proj_b, n2g, n2b,
                                   wbuf + 36864, fc1_b, wbuf + 73728, fc2_b, out);
}